// Round 5
// baseline (414.662 us; speedup 1.0000x reference)
//
#include <hip/hip_runtime.h>
#include <math.h>

#define Nn 32
#define Cc 64
#define Tt 128
#define Vv 25
#define Kk 204800   // C*T*V
#define Hh 256
#define Ee 4
#define KC 256             // k-chunk per block
#define KB 4               // W0 rows per wave-private buffer (4 rows x 64 h = 1 KB)
#define NSTEP (KC / KB)    // 64
#define NBLK_A 800         // Kk / KC

__device__ __forceinline__ float elu1(float v) { return v > 0.0f ? v : expm1f(v); }

typedef const __attribute__((address_space(1))) void* gvp;
typedef __attribute__((address_space(3))) void* lvp;
// async DMA global->LDS, 16B per lane, lands at ldsbase + lane*16
__device__ __forceinline__ void gl_lds16(const void* g, void* l) {
  __builtin_amdgcn_global_load_lds((gvp)g, (lvp)l, 16, 0, 0);
}

// ---------------- Kernel A: split-K  partials[b][n][h] = sum_{k in chunk b} x[n,k]*W0[k,h]
// BARRIER-FREE K-loop: wave w privately owns h-slice [64w, 64w+64) and streams its own
// W0 sub-tiles via per-wave global_load_lds with a depth-3 counted-vmcnt pipeline.
// No cross-wave LDS sharing of W0 => no s_barrier in the loop => no convoy stalls
// (round-4 PMC: 130us @ VALU 20%, HBM 13%, Occ 21% -- sync-bound, not BW-bound).
// xs[32][256] staged once (1 barrier total), XOR-swizzled (c4 ^ (n>>2)) so the 8
// n-row broadcast reads hit 8 distinct bank quads (round-4 conflicts: 6.5M).
// LDS 48KB -> 3 blocks/CU, 12 waves/CU.
__global__ __launch_bounds__(256) void kA(const float* __restrict__ x,
                                          const float* __restrict__ W0,
                                          float* __restrict__ partials) {
  __shared__ float xs[Nn][KC];             // 32 KB, chunk-swizzled
  __shared__ float wsl[4][4][KB][64];      // [wave][buf][k][h] 16 KB, wave-private
  const int tid  = threadIdx.x;
  const int lane = tid & 63;
  const int wv   = tid >> 6;
  const int b  = blockIdx.x;
  const int k0 = b * KC;

  // ---- stage xs with XOR chunk swizzle: chunk c4 of row r stored at c4 ^ (r>>2)
  for (int i = tid; i < Nn * (KC / 4); i += 256) {
    int r  = i >> 6;            // row 0..31
    int c4 = i & 63;            // float4 chunk 0..63
    float4 v = *(const float4*)(x + (size_t)r * Kk + k0 + c4 * 4);
    *(float4*)&xs[r][(c4 ^ (r >> 2)) * 4] = v;
  }
  // retire all xs global loads so vmcnt counts ONLY our W0 DMAs below
  asm volatile("s_waitcnt vmcnt(0)" ::: "memory");

  // ---- prologue: issue depth-3 per-wave W0 DMAs (1 KB each: 4 k-rows x 64 h)
  // lane l -> k-row (l>>4), h-offset (l&15)*4 within this wave's 64-h slice
  const int hbase = wv * 64;
  const size_t gking = (size_t)(lane >> 4) * Hh + hbase + (lane & 15) * 4;
  #pragma unroll
  for (int s = 0; s < 3; ++s)
    gl_lds16(W0 + (size_t)(k0 + s * KB) * Hh + gking, &wsl[wv][s][0][0]);

  // publish xs (per-wave ds_writes drained, then block-wide barrier)
  asm volatile("s_waitcnt lgkmcnt(0)" ::: "memory");
  __syncthreads();   // the ONLY barrier

  const int j8 = lane >> 3;       // 0..7 -> n0 = j8*4
  const int n0 = j8 * 4;
  const int h0 = (lane & 7) * 8;  // within wave slice

  float acc[4][8];
  #pragma unroll
  for (int i = 0; i < 4; ++i)
    #pragma unroll
    for (int c = 0; c < 8; ++c) acc[i][c] = 0.0f;

  for (int step = 0; step < NSTEP; ++step) {
    // retire buf[step] (this wave's oldest DMA) without draining the rest
    if (step < NSTEP - 2) {
      asm volatile("s_waitcnt vmcnt(2)" ::: "memory");
    } else if (step == NSTEP - 2) {
      asm volatile("s_waitcnt vmcnt(1)" ::: "memory");
    } else {
      asm volatile("s_waitcnt vmcnt(0)" ::: "memory");
    }
    __builtin_amdgcn_sched_barrier(0);

    // refill: issue buf[step+3] into the slot freed at step-1 (wave-private, no races)
    if (step + 3 < NSTEP)
      gl_lds16(W0 + (size_t)(k0 + (step + 3) * KB) * Hh + gking,
               &wsl[wv][(step + 3) & 3][0][0]);

    const int slot = step & 3;
    // xs chunk for this step: swizzled column (step ^ j8), same for all 4 n-rows
    const int xcol = (step ^ j8) * 4;
    float4 xv[4];
    #pragma unroll
    for (int i = 0; i < 4; ++i)
      xv[i] = *(const float4*)&xs[n0 + i][xcol];   // 8-lane broadcast, 8 bank quads
    #pragma unroll
    for (int u = 0; u < 4; ++u) {
      const float* wp = &wsl[wv][slot][u][h0];
      float4 wa = *(const float4*)(wp);
      float4 wb = *(const float4*)(wp + 4);
      #pragma unroll
      for (int i = 0; i < 4; ++i) {
        float xu = (u == 0) ? xv[i].x : (u == 1) ? xv[i].y : (u == 2) ? xv[i].z : xv[i].w;
        acc[i][0] = fmaf(xu, wa.x, acc[i][0]);
        acc[i][1] = fmaf(xu, wa.y, acc[i][1]);
        acc[i][2] = fmaf(xu, wa.z, acc[i][2]);
        acc[i][3] = fmaf(xu, wa.w, acc[i][3]);
        acc[i][4] = fmaf(xu, wb.x, acc[i][4]);
        acc[i][5] = fmaf(xu, wb.y, acc[i][5]);
        acc[i][6] = fmaf(xu, wb.z, acc[i][6]);
        acc[i][7] = fmaf(xu, wb.w, acc[i][7]);
      }
    }
  }

  #pragma unroll
  for (int i = 0; i < 4; ++i) {
    float* pp = partials + ((size_t)(b * Nn + n0 + i) << 8) + hbase + h0;
    *(float4*)(pp)     = make_float4(acc[i][0], acc[i][1], acc[i][2], acc[i][3]);
    *(float4*)(pp + 4) = make_float4(acc[i][4], acc[i][5], acc[i][6], acc[i][7]);
  }
}

// ---------------- Kernel B1: reduce 800 partials, + b0, ELU  -> hb[n][h]
__global__ __launch_bounds__(256) void kB1(const float* __restrict__ partials,
                                           const float* __restrict__ b0,
                                           float* __restrict__ hb) {
  const int n  = blockIdx.x >> 3;
  const int hc = blockIdx.x & 7;
  const int tid = threadIdx.x;
  const int hl = tid & 31;
  const int bsub = tid >> 5;     // 8 sub-reducers x 100 each
  const int h = hc * 32 + hl;
  float s = 0.0f;
  for (int j = 0; j < 100; ++j) {
    int b = bsub * 100 + j;
    s += partials[((size_t)(b * Nn + n) << 8) + h];
  }
  __shared__ float red[8][32];
  red[bsub][hl] = s;
  __syncthreads();
  if (tid < 32) {
    float tot = 0.0f;
    #pragma unroll
    for (int sI = 0; sI < 8; ++sI) tot += red[sI][tid];
    int hh = hc * 32 + tid;
    hb[n * Hh + hh] = elu1(tot + b0[hh]);
  }
}

// ---------------- Kernel B2: h2 = elu(hb@W1+b1); logits = h2@W2+b2; softmax -> wgt[n][e]
__global__ __launch_bounds__(256) void kB2(const float* __restrict__ hb,
                                           const float* __restrict__ W1,
                                           const float* __restrict__ b1,
                                           const float* __restrict__ W2,
                                           const float* __restrict__ b2,
                                           float* __restrict__ wgt) {
  const int n = blockIdx.x;
  const int tid = threadIdx.x;
  __shared__ float hbs[Hh];
  hbs[tid] = hb[n * Hh + tid];
  __syncthreads();
  float s = b1[tid];
  for (int j = 0; j < Hh; ++j) s = fmaf(hbs[j], W1[j * Hh + tid], s);
  float h2 = elu1(s);
  float le[Ee];
  #pragma unroll
  for (int e = 0; e < Ee; ++e) le[e] = h2 * W2[tid * Ee + e];
  __shared__ float red[Ee][4];
  const int lane = tid & 63;
  const int wid  = tid >> 6;
  #pragma unroll
  for (int e = 0; e < Ee; ++e) {
    float v = le[e];
    for (int off = 32; off > 0; off >>= 1) v += __shfl_down(v, off, 64);
    if (lane == 0) red[e][wid] = v;
  }
  __syncthreads();
  if (tid == 0) {
    float lg[Ee];
    float m = -1e30f;
    #pragma unroll
    for (int e = 0; e < Ee; ++e) {
      lg[e] = red[e][0] + red[e][1] + red[e][2] + red[e][3] + b2[e];
      m = fmaxf(m, lg[e]);
    }
    float den = 0.0f;
    #pragma unroll
    for (int e = 0; e < Ee; ++e) { lg[e] = expf(lg[e] - m); den += lg[e]; }
    float inv = 1.0f / den;
    #pragma unroll
    for (int e = 0; e < Ee; ++e) wgt[n * Ee + e] = lg[e] * inv;
  }
}

// ---------------- Kernel C: per (n,t): AS[v][w] = sum_e wgt[n][e]*A[e][t][v][w];
//                  out[n][c][t][w] = sum_v x[n][c][t][v] * AS[v][w]
#define ASW 28   // padded AS row
#define XTS 68   // padded xT row
__global__ __launch_bounds__(256) void kC(const float* __restrict__ x,
                                          const float* __restrict__ A,
                                          const float* __restrict__ wgt,
                                          float* __restrict__ out) {
  const int blk = blockIdx.x;
  const int n  = blk >> 6;       // 32 n
  const int tp = blk & 63;       // 64 t-pairs
  const int tid = threadIdx.x;
  const int tsub = tid >> 7;     // which t of the pair
  const int tl = tid & 127;
  const int t = tp * 2 + tsub;

  __shared__ float AS[2][Vv][ASW];
  __shared__ float xT[2][Vv][XTS];

  float wv[Ee];
  #pragma unroll
  for (int e = 0; e < Ee; ++e) wv[e] = wgt[n * Ee + e];

  for (int idx = tl; idx < Vv * ASW; idx += 128) {
    int v = idx / ASW;
    int w = idx - v * ASW;
    float s = 0.0f;
    if (w < Vv) {
      #pragma unroll
      for (int e = 0; e < Ee; ++e)
        s = fmaf(wv[e], A[((size_t)(e * Tt + t) * Vv + v) * Vv + w], s);
    }
    AS[tsub][v][w] = s;
  }
  const float* xb = x + (size_t)n * (Cc * Tt * Vv) + (size_t)t * Vv;
  for (int idx = tl; idx < Cc * Vv; idx += 128) {
    int c = idx / Vv;
    int v = idx - c * Vv;
    xT[tsub][v][c] = xb[(size_t)c * (Tt * Vv) + v];
  }
  __syncthreads();

  const int ct = tl & 15;        // c0 = ct*4
  const int wq = tl >> 4;        // 0..7, active if <7
  if (wq < 7) {
    const int c0 = ct * 4;
    const int w0 = wq * 4;
    float acc[4][4];
    #pragma unroll
    for (int i = 0; i < 4; ++i)
      #pragma unroll
      for (int j = 0; j < 4; ++j) acc[i][j] = 0.0f;
    #pragma unroll 5
    for (int v = 0; v < Vv; ++v) {
      float4 a4 = *(const float4*)&AS[tsub][v][w0];
      float4 x4 = *(const float4*)&xT[tsub][v][c0];
      const float xr[4] = {x4.x, x4.y, x4.z, x4.w};
      const float ar[4] = {a4.x, a4.y, a4.z, a4.w};
      #pragma unroll
      for (int i = 0; i < 4; ++i)
        #pragma unroll
        for (int j = 0; j < 4; ++j)
          acc[i][j] = fmaf(xr[i], ar[j], acc[i][j]);
    }
    #pragma unroll
    for (int i = 0; i < 4; ++i) {
      int c = c0 + i;
      float* ob = out + ((size_t)(n * Cc + c) * Tt + t) * Vv;
      #pragma unroll
      for (int j = 0; j < 4; ++j) {
        int w = w0 + j;
        if (w < Vv) ob[w] = acc[i][j];
      }
    }
  }
}

extern "C" void kernel_launch(void* const* d_in, const int* in_sizes, int n_in,
                              void* d_out, int out_size, void* d_ws, size_t ws_size,
                              hipStream_t stream) {
  const float* x  = (const float*)d_in[0];
  const float* W0 = (const float*)d_in[1];
  const float* b0 = (const float*)d_in[2];
  const float* W1 = (const float*)d_in[3];
  const float* b1 = (const float*)d_in[4];
  const float* W2 = (const float*)d_in[5];
  const float* b2 = (const float*)d_in[6];
  const float* A  = (const float*)d_in[7];
  float* out = (float*)d_out;

  float* partials = (float*)d_ws;                          // 800*32*256 floats = 26.2 MB
  float* hb  = partials + (size_t)NBLK_A * Nn * Hh;        // 8192 floats
  float* wgt = hb + Nn * Hh;                               // 128 floats

  kA <<<NBLK_A,  256, 0, stream>>>(x, W0, partials);
  kB1<<<256,     256, 0, stream>>>(partials, b0, hb);
  kB2<<<Nn,      256, 0, stream>>>(hb, W1, b1, W2, b2, wgt);
  kC <<<Nn * 64, 256, 0, stream>>>(x, A, wgt, out);
}

// Round 6
// 390.016 us; speedup vs baseline: 1.0632x; 1.0632x over previous
//
#include <hip/hip_runtime.h>
#include <math.h>

#define Nn 32
#define Cc 64
#define Tt 128
#define Vv 25
#define Kk 204800   // C*T*V
#define Hh 256
#define Ee 4
#define KC 256             // k-chunk per block
#define XPAD 36            // xsT row pad (144B: 16B-aligned, conflict-free-ish)
#define NBLK_A 800         // Kk / KC

__device__ __forceinline__ float elu1(float v) { return v > 0.0f ? v : expm1f(v); }

// ---------------- Kernel A: split-K  partials[b][n][h] = sum_{k in chunk b} x[n,k]*W0[k,h]
// REGISTER-STREAMED W0: no LDS round-trip for the 210MB streaming operand.
// (r4/r5 PMC: every DMA-staged variant sat at ~130-140us with VALU 18%, HBM 13%,
// conflicts 0, occupancy 21% -- the global_load_lds->ds_read path was the invariant.
// Plain coalesced float4 register loads are the proven 6.3+ TB/s path.)
// Layout: lane owns h-cols [4*lane, 4*lane+4) (64 lanes = full 1KB W0 row, no dup);
// wave wv owns n-rows [8*wv, 8*wv+8). x^T staged once in LDS (wave-uniform reads,
// broadcast = free). 36.9KB LDS, ~90 VGPR -> 4 blocks/CU, 16 waves/CU; 800 blocks
// all resident in one round.
__global__ __launch_bounds__(256, 4) void kA(const float* __restrict__ x,
                                             const float* __restrict__ W0,
                                             float* __restrict__ partials) {
  __shared__ float xsT[KC][XPAD];    // [k][n], padded row: 36.9 KB
  const int tid  = threadIdx.x;
  const int lane = tid & 63;
  const int wv   = tid >> 6;
  const int b  = blockIdx.x;
  const int k0 = b * KC;

  // stage x^T: thread i handles (n = i>>6, c4 = i&63): float4 of x[n][k0+4c4 ..]
  for (int i = tid; i < Nn * (KC / 4); i += 256) {
    int n  = i >> 6;
    int c4 = i & 63;
    float4 v = *(const float4*)(x + (size_t)n * Kk + k0 + c4 * 4);
    xsT[c4 * 4 + 0][n] = v.x;
    xsT[c4 * 4 + 1][n] = v.y;
    xsT[c4 * 4 + 2][n] = v.z;
    xsT[c4 * 4 + 3][n] = v.w;
  }
  __syncthreads();   // the only barrier

  const int n0 = wv * 8;
  const int h4 = lane * 4;

  float acc[8][4];
  #pragma unroll
  for (int j = 0; j < 8; ++j)
    #pragma unroll
    for (int c = 0; c < 4; ++c) acc[j][c] = 0.0f;

  const float* wp = W0 + (size_t)k0 * Hh + h4;
  #pragma unroll 8
  for (int k = 0; k < KC; ++k) {
    float4 w = *(const float4*)(wp);
    wp += Hh;
    float4 xa = *(const float4*)&xsT[k][n0];       // wave-uniform: broadcast
    float4 xb = *(const float4*)&xsT[k][n0 + 4];
    const float xr[8] = {xa.x, xa.y, xa.z, xa.w, xb.x, xb.y, xb.z, xb.w};
    #pragma unroll
    for (int j = 0; j < 8; ++j) {
      acc[j][0] = fmaf(xr[j], w.x, acc[j][0]);
      acc[j][1] = fmaf(xr[j], w.y, acc[j][1]);
      acc[j][2] = fmaf(xr[j], w.z, acc[j][2]);
      acc[j][3] = fmaf(xr[j], w.w, acc[j][3]);
    }
  }

  #pragma unroll
  for (int j = 0; j < 8; ++j) {
    float* pp = partials + ((size_t)(b * Nn + n0 + j) << 8) + h4;
    *(float4*)(pp) = make_float4(acc[j][0], acc[j][1], acc[j][2], acc[j][3]);
  }
}

// ---------------- Kernel B1: reduce 800 partials, + b0, ELU  -> hb[n][h]
__global__ __launch_bounds__(256) void kB1(const float* __restrict__ partials,
                                           const float* __restrict__ b0,
                                           float* __restrict__ hb) {
  const int n  = blockIdx.x >> 3;
  const int hc = blockIdx.x & 7;
  const int tid = threadIdx.x;
  const int hl = tid & 31;
  const int bsub = tid >> 5;     // 8 sub-reducers x 100 each
  const int h = hc * 32 + hl;
  float s = 0.0f;
  for (int j = 0; j < 100; ++j) {
    int b = bsub * 100 + j;
    s += partials[((size_t)(b * Nn + n) << 8) + h];
  }
  __shared__ float red[8][32];
  red[bsub][hl] = s;
  __syncthreads();
  if (tid < 32) {
    float tot = 0.0f;
    #pragma unroll
    for (int sI = 0; sI < 8; ++sI) tot += red[sI][tid];
    int hh = hc * 32 + tid;
    hb[n * Hh + hh] = elu1(tot + b0[hh]);
  }
}

// ---------------- Kernel B2: h2 = elu(hb@W1+b1); logits = h2@W2+b2; softmax -> wgt[n][e]
__global__ __launch_bounds__(256) void kB2(const float* __restrict__ hb,
                                           const float* __restrict__ W1,
                                           const float* __restrict__ b1,
                                           const float* __restrict__ W2,
                                           const float* __restrict__ b2,
                                           float* __restrict__ wgt) {
  const int n = blockIdx.x;
  const int tid = threadIdx.x;
  __shared__ float hbs[Hh];
  hbs[tid] = hb[n * Hh + tid];
  __syncthreads();
  float s = b1[tid];
  for (int j = 0; j < Hh; ++j) s = fmaf(hbs[j], W1[j * Hh + tid], s);
  float h2 = elu1(s);
  float le[Ee];
  #pragma unroll
  for (int e = 0; e < Ee; ++e) le[e] = h2 * W2[tid * Ee + e];
  __shared__ float red[Ee][4];
  const int lane = tid & 63;
  const int wid  = tid >> 6;
  #pragma unroll
  for (int e = 0; e < Ee; ++e) {
    float v = le[e];
    for (int off = 32; off > 0; off >>= 1) v += __shfl_down(v, off, 64);
    if (lane == 0) red[e][wid] = v;
  }
  __syncthreads();
  if (tid == 0) {
    float lg[Ee];
    float m = -1e30f;
    #pragma unroll
    for (int e = 0; e < Ee; ++e) {
      lg[e] = red[e][0] + red[e][1] + red[e][2] + red[e][3] + b2[e];
      m = fmaxf(m, lg[e]);
    }
    float den = 0.0f;
    #pragma unroll
    for (int e = 0; e < Ee; ++e) { lg[e] = expf(lg[e] - m); den += lg[e]; }
    float inv = 1.0f / den;
    #pragma unroll
    for (int e = 0; e < Ee; ++e) wgt[n * Ee + e] = lg[e] * inv;
  }
}

// ---------------- Kernel C: per (n,t): AS[v][w] = sum_e wgt[n][e]*A[e][t][v][w];
//                  out[n][c][t][w] = sum_v x[n][c][t][v] * AS[v][w]
#define ASW 28   // padded AS row
#define XTS 68   // padded xT row
__global__ __launch_bounds__(256) void kC(const float* __restrict__ x,
                                          const float* __restrict__ A,
                                          const float* __restrict__ wgt,
                                          float* __restrict__ out) {
  const int blk = blockIdx.x;
  const int n  = blk >> 6;       // 32 n
  const int tp = blk & 63;       // 64 t-pairs
  const int tid = threadIdx.x;
  const int tsub = tid >> 7;     // which t of the pair
  const int tl = tid & 127;
  const int t = tp * 2 + tsub;

  __shared__ float AS[2][Vv][ASW];
  __shared__ float xT[2][Vv][XTS];

  float wv[Ee];
  #pragma unroll
  for (int e = 0; e < Ee; ++e) wv[e] = wgt[n * Ee + e];

  for (int idx = tl; idx < Vv * ASW; idx += 128) {
    int v = idx / ASW;
    int w = idx - v * ASW;
    float s = 0.0f;
    if (w < Vv) {
      #pragma unroll
      for (int e = 0; e < Ee; ++e)
        s = fmaf(wv[e], A[((size_t)(e * Tt + t) * Vv + v) * Vv + w], s);
    }
    AS[tsub][v][w] = s;
  }
  const float* xb = x + (size_t)n * (Cc * Tt * Vv) + (size_t)t * Vv;
  for (int idx = tl; idx < Cc * Vv; idx += 128) {
    int c = idx / Vv;
    int v = idx - c * Vv;
    xT[tsub][v][c] = xb[(size_t)c * (Tt * Vv) + v];
  }
  __syncthreads();

  const int ct = tl & 15;        // c0 = ct*4
  const int wq = tl >> 4;        // 0..7, active if <7
  if (wq < 7) {
    const int c0 = ct * 4;
    const int w0 = wq * 4;
    float acc[4][4];
    #pragma unroll
    for (int i = 0; i < 4; ++i)
      #pragma unroll
      for (int j = 0; j < 4; ++j) acc[i][j] = 0.0f;
    #pragma unroll 5
    for (int v = 0; v < Vv; ++v) {
      float4 a4 = *(const float4*)&AS[tsub][v][w0];
      float4 x4 = *(const float4*)&xT[tsub][v][c0];
      const float xr[4] = {x4.x, x4.y, x4.z, x4.w};
      const float ar[4] = {a4.x, a4.y, a4.z, a4.w};
      #pragma unroll
      for (int i = 0; i < 4; ++i)
        #pragma unroll
        for (int j = 0; j < 4; ++j)
          acc[i][j] = fmaf(xr[i], ar[j], acc[i][j]);
    }
    #pragma unroll
    for (int i = 0; i < 4; ++i) {
      int c = c0 + i;
      float* ob = out + ((size_t)(n * Cc + c) * Tt + t) * Vv;
      #pragma unroll
      for (int j = 0; j < 4; ++j) {
        int w = w0 + j;
        if (w < Vv) ob[w] = acc[i][j];
      }
    }
  }
}

extern "C" void kernel_launch(void* const* d_in, const int* in_sizes, int n_in,
                              void* d_out, int out_size, void* d_ws, size_t ws_size,
                              hipStream_t stream) {
  const float* x  = (const float*)d_in[0];
  const float* W0 = (const float*)d_in[1];
  const float* b0 = (const float*)d_in[2];
  const float* W1 = (const float*)d_in[3];
  const float* b1 = (const float*)d_in[4];
  const float* W2 = (const float*)d_in[5];
  const float* b2 = (const float*)d_in[6];
  const float* A  = (const float*)d_in[7];
  float* out = (float*)d_out;

  float* partials = (float*)d_ws;                          // 800*32*256 floats = 26.2 MB
  float* hb  = partials + (size_t)NBLK_A * Nn * Hh;        // 8192 floats
  float* wgt = hb + Nn * Hh;                               // 128 floats

  kA <<<NBLK_A,  256, 0, stream>>>(x, W0, partials);
  kB1<<<256,     256, 0, stream>>>(partials, b0, hb);
  kB2<<<Nn,      256, 0, stream>>>(hb, W1, b1, W2, b2, wgt);
  kC <<<Nn * 64, 256, 0, stream>>>(x, A, wgt, out);
}